// Round 10
// baseline (15600.140 us; speedup 1.0000x reference)
//
#include <hip/hip_runtime.h>

// LSTM seq2seq: 1000 enc + 1000 dec steps, B=512, H=512, IN=OUT=1.
// Persistent plain-launch kernel; 256 blocks x 256 threads, 1 block/CU.
// Block (rb,hb): rb=bid>>5 owns batch rows [rb*64,+64); hb=bid&31 owns hidden
// cols [hb*16,+16) -> 64 gate cols. Row-group = 32 blocks sharing rb.
// ROUND 10: A/B isolation of round-9 regression. Barrier restored to the
// PROVEN round-6 form: wave0-only flag poll + post-poll __syncthreads
// (round-9's all-wave poll = 4x LLC poll traffic ~47 Greq/s, contending with
// staging/acks at the LLC ports -> suspected regression). Split-stage
// pipeline KEPT from round 9: stage group A (ks0-7), sync, issue group B
// while MFMA runs on A, sync, MFMA on B. A/B LDS chunks disjoint.
// h exchange: LDS staging via global_load_lds aux=17 (sc0|sc1, LLC-coherent
// across XCDs); h stores = 8B agent atomics; flag-broadcast barrier.
// Numerics: h fp16; W = W_hi(fp16) + W_lo(fp16*2048)/2048 in registers,
// two MFMA passes (f32 accum); HW transcendentals. [absmax 6.1e-5 r5/r6/r9]

typedef _Float16 f16x8 __attribute__((ext_vector_type(8)));
typedef _Float16 f16x4 __attribute__((ext_vector_type(4)));
typedef float    f32x4 __attribute__((ext_vector_type(4)));
typedef unsigned long long u64;

// 16B global->LDS async copy, sc0|sc1: read at LLC coherence point,
// correct for cross-XCD producers regardless of block placement.
#define GLOAD_LDS16(gp, lp)                                                    \
  __builtin_amdgcn_global_load_lds(                                            \
      (const __attribute__((address_space(1))) void*)(gp),                     \
      (__attribute__((address_space(3))) void*)(lp), 16, 0, 17)

__device__ __forceinline__ void store_h8_llc(_Float16* p, f16x4 v) {
  __hip_atomic_store((u64*)p, __builtin_bit_cast(u64, v),
                     __ATOMIC_RELAXED, __HIP_MEMORY_SCOPE_AGENT);
}

// sigmoid(x) = rcp(1 + e^-x); tanh via e^(-2|x|): both overflow-safe.
__device__ __forceinline__ float sigm(float x) {
  return __builtin_amdgcn_rcpf(1.0f + __expf(-x));
}
__device__ __forceinline__ float tanh_fast(float x) {
  float r = __expf(-2.0f*fabsf(x));
  float t = (1.0f - r)*__builtin_amdgcn_rcpf(1.0f + r);
  return copysignf(t, x);
}

__global__ void init_zero(float* __restrict__ out, int nout,
                          float* __restrict__ wsf, int nws) {
  int i = blockIdx.x*blockDim.x + threadIdx.x;
  int st = gridDim.x*blockDim.x;
  // agent-scope write-through stores: nothing left dirty in any L2
  for (int j=i; j<nout; j+=st)
    __hip_atomic_store(&out[j], 0.f, __ATOMIC_RELAXED, __HIP_MEMORY_SCOPE_AGENT);
  for (int j=i; j<nws;  j+=st)
    __hip_atomic_store(&wsf[j], 0.f, __ATOMIC_RELAXED, __HIP_MEMORY_SCOPE_AGENT);
}

__global__ __launch_bounds__(256, 1) void lstm_main(
    const float* __restrict__ xin,                              // [1000][512]
    const float* __restrict__ encWih, const float* __restrict__ encWhh,
    const float* __restrict__ enc_bih, const float* __restrict__ enc_bhh,
    const float* __restrict__ decWih, const float* __restrict__ decWhh,
    const float* __restrict__ dec_bih, const float* __restrict__ dec_bhh,
    const float* __restrict__ linW, const float* __restrict__ linb,
    float* __restrict__ out,                                    // [1000][512]
    _Float16* __restrict__ hbuf,                                // [2][512][512]
    int* __restrict__ flags)                                    // 256 x 128B lines
{
  // h tile in FRAGMENT order: chunk = slice*2048 + (ks*2+half)*64 + lane ->
  // MFMA A-fragment reads are lane-linear ds_read_b128 (conflict-free).
  // Group A = pairs 0..15 (ks 0..7), group B = pairs 16..31 (ks 8..15).
  __shared__ f16x8 h_lds[4096];     // 64 KB
  __shared__ float gates[64][68];   // 17408 B; +4 pad kills stride conflicts

  const int bid = blockIdx.x, tid = threadIdx.x;
  const int rb = bid >> 5, hb = bid & 31;
  const int wid = tid >> 6, lane = tid & 63;
  const int wrow = wid >> 1, wcol = wid & 1;         // wave grid 2x2
  const int lcol = lane & 15, lq = lane >> 4, kq = lq*8;

  // cell-update role: thread owns 4 cells (b_local, hidden cols u0..u0+3)
  const int b_local = tid >> 2, u0 = (tid & 3)*4;
  const int bg = rb*64 + b_local;
  const int jh0 = hb*16 + u0;

  float linw[4];
  #pragma unroll
  for (int u=0; u<4; ++u) linw[u] = linW[jh0+u];
  const float linbv = linb[0];

  f16x8 wHi[2][16], wLo[2][16];
  float biasv[16], wihv[16];
  float c[4] = {0.f, 0.f, 0.f, 0.f};
  int* myflag = flags + (rb*32 + hb)*32;               // own 128B line
  const int* pollp = flags + (rb*32 + (lane & 31))*32; // lane's producer line

  // staging source offsets: chunk c=i*256+tid -> fragment-order LDS.
  // (i&7)<4 => pair 0..15 (group A, ks0-7); else pair 16..31 (group B, ks8-15).
  int goff[16];
  #pragma unroll
  for (int i=0; i<16; ++i) {
    const int cch = i*256 + tid;
    const int pair = (cch >> 6) & 31;
    const int ks = pair >> 1, half = pair & 1;
    const int row_local = (cch >> 11)*32 + half*16 + lcol;
    goff[i] = row_local*512 + ks*32 + kq;
  }

  auto loadW = [&](const float* Whh, const float* bih, const float* bhh,
                   const float* Wih) {
    #pragma unroll
    for (int ct=0; ct<2; ++ct) {
      const int g = wcol*2 + ct;
      const float* wr = Whh + (size_t)(g*512 + hb*16 + lcol)*512;
      #pragma unroll
      for (int ks=0; ks<16; ++ks) {
        f16x8 hi, lo;
        #pragma unroll
        for (int i=0; i<8; ++i) {
          float w = wr[ks*32 + kq + i];
          _Float16 hh = (_Float16)w;
          float hf = (float)hh;
          float rem = (w - hf)*2048.0f;
          if (fabsf(hf) < 6.104e-5f) { hh = (_Float16)0.0f; rem = w*2048.0f; }
          hi[i] = hh; lo[i] = (_Float16)rem;
        }
        wHi[ct][ks] = hi; wLo[ct][ks] = lo;
      }
    }
    #pragma unroll
    for (int g=0; g<4; ++g)
      #pragma unroll
      for (int u=0; u<4; ++u) {
        int j = g*512 + jh0 + u;
        biasv[g*4+u] = bih[j] + bhh[j];
        wihv[g*4+u]  = Wih[j];
      }
  };

  loadW(encWhh, enc_bih, enc_bhh, encWih);

  for (int s=0; s<2000; ++s) {
    if (s == 1000) loadW(decWhh, dec_bih, dec_bhh, decWih);
    const bool dec = (s >= 1000);
    const int td = s - 1000;
    const _Float16* hr = hbuf + (size_t)((s+1)&1)*(512*512);  // reads h_{s-1}
    _Float16*       hw = hbuf + (size_t)( s   &1)*(512*512);  // writes h_s

    const _Float16* hrb = hr + (size_t)rb*64*512;
    f16x8* ldst = &h_lds[(size_t)wid*64];

    // hoist x: its LLC latency hides under staging drain
    float x;
    if (!dec) x = xin[(size_t)s*512 + bg];
    else if (td == 0) x = 0.0f;
    else x = __hip_atomic_load(&out[(size_t)(td-1)*512 + bg],
                               __ATOMIC_RELAXED, __HIP_MEMORY_SCOPE_AGENT);

    // ---- stage group A (ks 0..7): i in {0,1,2,3,8,9,10,11} ----
    #pragma unroll
    for (int i=0; i<16; ++i)
      if ((i & 7) < 4) GLOAD_LDS16(hrb + goff[i], ldst + i*256);
    __syncthreads();   // (a1) A staged block-wide (compiler drains vmcnt)

    // ---- issue group B (ks 8..15) while computing MFMA on A ----
    #pragma unroll
    for (int i=0; i<16; ++i)
      if ((i & 7) >= 4) GLOAD_LDS16(hrb + goff[i], ldst + i*256);

    f32x4 accH[2][2], accL[2][2];
    #pragma unroll
    for (int rt=0; rt<2; ++rt)
      #pragma unroll
      for (int ctt=0; ctt<2; ++ctt) {
        accH[rt][ctt] = {0.f,0.f,0.f,0.f};
        accL[rt][ctt] = {0.f,0.f,0.f,0.f};
      }
    const f16x8* Ha = &h_lds[(size_t)wrow*2048];

    #pragma unroll
    for (int ks=0; ks<8; ++ks) {
      const f16x8 a0 = Ha[ks*128 + lane];
      const f16x8 a1 = Ha[ks*128 + 64 + lane];
      accH[0][0] = __builtin_amdgcn_mfma_f32_16x16x32_f16(a0, wHi[0][ks], accH[0][0], 0,0,0);
      accH[1][0] = __builtin_amdgcn_mfma_f32_16x16x32_f16(a1, wHi[0][ks], accH[1][0], 0,0,0);
      accH[0][1] = __builtin_amdgcn_mfma_f32_16x16x32_f16(a0, wHi[1][ks], accH[0][1], 0,0,0);
      accH[1][1] = __builtin_amdgcn_mfma_f32_16x16x32_f16(a1, wHi[1][ks], accH[1][1], 0,0,0);
      accL[0][0] = __builtin_amdgcn_mfma_f32_16x16x32_f16(a0, wLo[0][ks], accL[0][0], 0,0,0);
      accL[1][0] = __builtin_amdgcn_mfma_f32_16x16x32_f16(a1, wLo[0][ks], accL[1][0], 0,0,0);
      accL[0][1] = __builtin_amdgcn_mfma_f32_16x16x32_f16(a0, wLo[1][ks], accL[0][1], 0,0,0);
      accL[1][1] = __builtin_amdgcn_mfma_f32_16x16x32_f16(a1, wLo[1][ks], accL[1][1], 0,0,0);
    }
    __syncthreads();   // (a2) B staged block-wide; all waves past A reads

    #pragma unroll
    for (int ks=8; ks<16; ++ks) {
      const f16x8 a0 = Ha[ks*128 + lane];
      const f16x8 a1 = Ha[ks*128 + 64 + lane];
      accH[0][0] = __builtin_amdgcn_mfma_f32_16x16x32_f16(a0, wHi[0][ks], accH[0][0], 0,0,0);
      accH[1][0] = __builtin_amdgcn_mfma_f32_16x16x32_f16(a1, wHi[0][ks], accH[1][0], 0,0,0);
      accH[0][1] = __builtin_amdgcn_mfma_f32_16x16x32_f16(a0, wHi[1][ks], accH[0][1], 0,0,0);
      accH[1][1] = __builtin_amdgcn_mfma_f32_16x16x32_f16(a1, wHi[1][ks], accH[1][1], 0,0,0);
      accL[0][0] = __builtin_amdgcn_mfma_f32_16x16x32_f16(a0, wLo[0][ks], accL[0][0], 0,0,0);
      accL[1][0] = __builtin_amdgcn_mfma_f32_16x16x32_f16(a1, wLo[0][ks], accL[1][0], 0,0,0);
      accL[0][1] = __builtin_amdgcn_mfma_f32_16x16x32_f16(a0, wLo[1][ks], accL[0][1], 0,0,0);
      accL[1][1] = __builtin_amdgcn_mfma_f32_16x16x32_f16(a1, wLo[1][ks], accL[1][1], 0,0,0);
    }

    // C-layout (m89): col = lane&15, row = (lane>>4)*4 + i
    #pragma unroll
    for (int rt=0; rt<2; ++rt)
      #pragma unroll
      for (int ctt=0; ctt<2; ++ctt) {
        f32x4 v = accH[rt][ctt] + accL[rt][ctt]*(1.0f/2048.0f);
        const int col  = wcol*32 + ctt*16 + lcol;
        const int row0 = wrow*32 + rt*16 + lq*4;
        #pragma unroll
        for (int i=0; i<4; ++i) gates[row0+i][col] = v[i];
      }
    __syncthreads();   // (b)

    // ---- pointwise LSTM cell update ----
    const f32x4 gi = *reinterpret_cast<const f32x4*>(&gates[b_local][ 0 + u0]);
    const f32x4 gf = *reinterpret_cast<const f32x4*>(&gates[b_local][16 + u0]);
    const f32x4 gg = *reinterpret_cast<const f32x4*>(&gates[b_local][32 + u0]);
    const f32x4 go = *reinterpret_cast<const f32x4*>(&gates[b_local][48 + u0]);

    f16x4 hv4;
    float sp = 0.f;
    #pragma unroll
    for (int u=0; u<4; ++u) {
      float ai = gi[u] + biasv[ 0+u] + x*wihv[ 0+u];
      float af = gf[u] + biasv[ 4+u] + x*wihv[ 4+u];
      float ag = gg[u] + biasv[ 8+u] + x*wihv[ 8+u];
      float ao = go[u] + biasv[12+u] + x*wihv[12+u];
      float iv = sigm(ai);
      float fv = sigm(af);
      float gv = tanh_fast(ag);
      float ov = sigm(ao);
      float cn = fv*c[u] + iv*gv;
      c[u] = cn;
      float hv = ov*tanh_fast(cn);
      hv4[u] = (_Float16)hv;
      sp += hv*linw[u];
    }
    store_h8_llc(hw + (size_t)bg*512 + jh0, hv4);   // 8B write-through to LLC

    if (dec) {  // pred partial: 4-lane reduce, one atomic into d_out
      sp += __shfl_xor(sp, 1);
      sp += __shfl_xor(sp, 2);
      if ((tid & 3) == 0) {
        float v = sp + (hb == 0 ? linbv : 0.f);
        __hip_atomic_fetch_add(&out[(size_t)td*512 + bg], v,
                               __ATOMIC_RELAXED, __HIP_MEMORY_SCOPE_AGENT);
      }
    }

    // ---- row-group barrier (round-6 form): wave0-only poll + handoff ----
    if (s != 1999) {
      asm volatile("s_waitcnt vmcnt(0)" ::: "memory");  // h stores/atomics acked
      __syncthreads();                                  // (c) block drained
      const int av = s + 1;
      if (tid == 0)
        __hip_atomic_store(myflag, av, __ATOMIC_RELAXED, __HIP_MEMORY_SCOPE_AGENT);
      if (wid == 0) {      // 64 lanes poll 32 producer flags (2 lanes/flag)
        while (!__all(__hip_atomic_load(pollp, __ATOMIC_RELAXED,
                                        __HIP_MEMORY_SCOPE_AGENT) >= av)) { }
      }
      __syncthreads();     // (d) handoff: all waves released by wave0
    }
  }
}

extern "C" void kernel_launch(void* const* d_in, const int* in_sizes, int n_in,
                              void* d_out, int out_size, void* d_ws, size_t ws_size,
                              hipStream_t stream) {
  const float* xin     = (const float*)d_in[0];
  const float* encWih  = (const float*)d_in[1];
  const float* encWhh  = (const float*)d_in[2];
  const float* enc_bih = (const float*)d_in[3];
  const float* enc_bhh = (const float*)d_in[4];
  const float* decWih  = (const float*)d_in[5];
  const float* decWhh  = (const float*)d_in[6];
  const float* dec_bih = (const float*)d_in[7];
  const float* dec_bhh = (const float*)d_in[8];
  const float* linW    = (const float*)d_in[9];
  const float* linb    = (const float*)d_in[10];
  float* out = (float*)d_out;
  char* ws = (char*)d_ws;
  int* flags = (int*)ws;                        // [0, 32KB): 256 x 128B flag lines
  _Float16* hbuf = (_Float16*)(ws + 32768);     // [32KB, +1MB): h double buffer

  // zero d_out (pred accumulator) + flags + h buffers, every launch
  init_zero<<<512, 256, 0, stream>>>(out, 1000*512, (float*)ws,
                                     (32768 + 2*512*512*2)/4);

  lstm_main<<<dim3(256), dim3(256), 0, stream>>>(
      xin, encWih, encWhh, enc_bih, enc_bhh,
      decWih, decWhh, dec_bih, dec_bhh,
      linW, linb, out, hbuf, flags);
}

// Round 11
// 14204.440 us; speedup vs baseline: 1.0983x; 1.0983x over previous
//
#include <hip/hip_runtime.h>

// LSTM seq2seq: 1000 enc + 1000 dec steps, B=512, H=512, IN=OUT=1.
// Persistent plain-launch kernel; 256 blocks x 256 threads, 1 block/CU.
// Block (rb,hb): rb=bid>>5 owns batch rows [rb*64,+64); hb=bid&31 owns hidden
// cols [hb*16,+16) -> 64 gate cols. Row-group = 32 blocks sharing rb.
// ROUND 11: best-of decomposition. r6=13.7 (wave0 poll, 1-batch stage),
// r9=14.7 (allwave poll, split), r10=15.6 (wave0, split) => split-stage was
// the regression (+0.85us/step: 2 serialized LLC RTs, MFMA 0.13us can't cover
// the 2nd); all-wave poll is a WIN (-0.45us/step: no wave0->handoff barrier).
// This round: single 16-load stage batch (r6) + all-wave poll, no post-poll
// barrier (r9). Poll-exit requires own block's flag (stored after sync(c)),
// so all waves finished prior-step LDS reads before any restaging [r9 ran
// correct]. h exchange: global_load_lds aux=17 (sc0|sc1, LLC-coherent);
// h stores = 8B agent atomics; flag-broadcast barrier.
// Numerics: h fp16; W = W_hi(fp16) + W_lo(fp16*2048)/2048 in registers,
// two MFMA passes (f32 accum); HW transcendentals. [absmax 6.1e-5 r5-r10]

typedef _Float16 f16x8 __attribute__((ext_vector_type(8)));
typedef _Float16 f16x4 __attribute__((ext_vector_type(4)));
typedef float    f32x4 __attribute__((ext_vector_type(4)));
typedef unsigned long long u64;

// 16B global->LDS async copy, sc0|sc1: read at LLC coherence point,
// correct for cross-XCD producers regardless of block placement.
#define GLOAD_LDS16(gp, lp)                                                    \
  __builtin_amdgcn_global_load_lds(                                            \
      (const __attribute__((address_space(1))) void*)(gp),                     \
      (__attribute__((address_space(3))) void*)(lp), 16, 0, 17)

__device__ __forceinline__ void store_h8_llc(_Float16* p, f16x4 v) {
  __hip_atomic_store((u64*)p, __builtin_bit_cast(u64, v),
                     __ATOMIC_RELAXED, __HIP_MEMORY_SCOPE_AGENT);
}

// sigmoid(x) = rcp(1 + e^-x); tanh via e^(-2|x|): both overflow-safe.
__device__ __forceinline__ float sigm(float x) {
  return __builtin_amdgcn_rcpf(1.0f + __expf(-x));
}
__device__ __forceinline__ float tanh_fast(float x) {
  float r = __expf(-2.0f*fabsf(x));
  float t = (1.0f - r)*__builtin_amdgcn_rcpf(1.0f + r);
  return copysignf(t, x);
}

__global__ void init_zero(float* __restrict__ out, int nout,
                          float* __restrict__ wsf, int nws) {
  int i = blockIdx.x*blockDim.x + threadIdx.x;
  int st = gridDim.x*blockDim.x;
  // agent-scope write-through stores: nothing left dirty in any L2
  for (int j=i; j<nout; j+=st)
    __hip_atomic_store(&out[j], 0.f, __ATOMIC_RELAXED, __HIP_MEMORY_SCOPE_AGENT);
  for (int j=i; j<nws;  j+=st)
    __hip_atomic_store(&wsf[j], 0.f, __ATOMIC_RELAXED, __HIP_MEMORY_SCOPE_AGENT);
}

__global__ __launch_bounds__(256, 1) void lstm_main(
    const float* __restrict__ xin,                              // [1000][512]
    const float* __restrict__ encWih, const float* __restrict__ encWhh,
    const float* __restrict__ enc_bih, const float* __restrict__ enc_bhh,
    const float* __restrict__ decWih, const float* __restrict__ decWhh,
    const float* __restrict__ dec_bih, const float* __restrict__ dec_bhh,
    const float* __restrict__ linW, const float* __restrict__ linb,
    float* __restrict__ out,                                    // [1000][512]
    _Float16* __restrict__ hbuf,                                // [2][512][512]
    int* __restrict__ flags)                                    // 256 x 128B lines
{
  // h tile in FRAGMENT order: chunk = slice*2048 + (ks*2+half)*64 + lane ->
  // MFMA A-fragment reads are lane-linear ds_read_b128 (conflict-free).
  __shared__ f16x8 h_lds[4096];     // 64 KB
  __shared__ float gates[64][68];   // 17408 B; +4 pad kills stride conflicts

  const int bid = blockIdx.x, tid = threadIdx.x;
  const int rb = bid >> 5, hb = bid & 31;
  const int wid = tid >> 6, lane = tid & 63;
  const int wrow = wid >> 1, wcol = wid & 1;         // wave grid 2x2
  const int lcol = lane & 15, lq = lane >> 4, kq = lq*8;

  // cell-update role: thread owns 4 cells (b_local, hidden cols u0..u0+3)
  const int b_local = tid >> 2, u0 = (tid & 3)*4;
  const int bg = rb*64 + b_local;
  const int jh0 = hb*16 + u0;

  float linw[4];
  #pragma unroll
  for (int u=0; u<4; ++u) linw[u] = linW[jh0+u];
  const float linbv = linb[0];

  f16x8 wHi[2][16], wLo[2][16];
  float biasv[16], wihv[16];
  float c[4] = {0.f, 0.f, 0.f, 0.f};
  int* myflag = flags + (rb*32 + hb)*32;               // own 128B line
  const int* pollp = flags + (rb*32 + (lane & 31))*32; // lane's producer line

  // staging source offsets: chunk c=i*256+tid -> fragment-order LDS
  int goff[16];
  #pragma unroll
  for (int i=0; i<16; ++i) {
    const int cch = i*256 + tid;
    const int pair = (cch >> 6) & 31;
    const int ks = pair >> 1, half = pair & 1;
    const int row_local = (cch >> 11)*32 + half*16 + lcol;
    goff[i] = row_local*512 + ks*32 + kq;
  }

  auto loadW = [&](const float* Whh, const float* bih, const float* bhh,
                   const float* Wih) {
    #pragma unroll
    for (int ct=0; ct<2; ++ct) {
      const int g = wcol*2 + ct;
      const float* wr = Whh + (size_t)(g*512 + hb*16 + lcol)*512;
      #pragma unroll
      for (int ks=0; ks<16; ++ks) {
        f16x8 hi, lo;
        #pragma unroll
        for (int i=0; i<8; ++i) {
          float w = wr[ks*32 + kq + i];
          _Float16 hh = (_Float16)w;
          float hf = (float)hh;
          float rem = (w - hf)*2048.0f;
          if (fabsf(hf) < 6.104e-5f) { hh = (_Float16)0.0f; rem = w*2048.0f; }
          hi[i] = hh; lo[i] = (_Float16)rem;
        }
        wHi[ct][ks] = hi; wLo[ct][ks] = lo;
      }
    }
    #pragma unroll
    for (int g=0; g<4; ++g)
      #pragma unroll
      for (int u=0; u<4; ++u) {
        int j = g*512 + jh0 + u;
        biasv[g*4+u] = bih[j] + bhh[j];
        wihv[g*4+u]  = Wih[j];
      }
  };

  loadW(encWhh, enc_bih, enc_bhh, encWih);

  for (int s=0; s<2000; ++s) {
    if (s == 1000) loadW(decWhh, dec_bih, dec_bhh, decWih);
    const bool dec = (s >= 1000);
    const int td = s - 1000;
    const _Float16* hr = hbuf + (size_t)((s+1)&1)*(512*512);  // reads h_{s-1}
    _Float16*       hw = hbuf + (size_t)( s   &1)*(512*512);  // writes h_s

    const _Float16* hrb = hr + (size_t)rb*64*512;
    f16x8* ldst = &h_lds[(size_t)wid*64];

    // hoist x: its LLC latency hides under staging drain
    float x;
    if (!dec) x = xin[(size_t)s*512 + bg];
    else if (td == 0) x = 0.0f;
    else x = __hip_atomic_load(&out[(size_t)(td-1)*512 + bg],
                               __ATOMIC_RELAXED, __HIP_MEMORY_SCOPE_AGENT);

    // ---- stage 64x512 fp16 h tile into LDS: ONE 16-load batch (max MLP) ----
    #pragma unroll
    for (int i=0; i<16; ++i)
      GLOAD_LDS16(hrb + goff[i], ldst + i*256);
    __syncthreads();   // (a) staged block-wide (compiler drains vmcnt)

    // ---- gates = h @ W^T (2-pass MFMA, wave tile 32 x 32) ----
    f32x4 accH[2][2], accL[2][2];
    #pragma unroll
    for (int rt=0; rt<2; ++rt)
      #pragma unroll
      for (int ctt=0; ctt<2; ++ctt) {
        accH[rt][ctt] = {0.f,0.f,0.f,0.f};
        accL[rt][ctt] = {0.f,0.f,0.f,0.f};
      }
    const f16x8* Ha = &h_lds[(size_t)wrow*2048];

    #pragma unroll
    for (int ks=0; ks<16; ++ks) {
      const f16x8 a0 = Ha[ks*128 + lane];        // ds_read_b128, lane-linear
      const f16x8 a1 = Ha[ks*128 + 64 + lane];
      accH[0][0] = __builtin_amdgcn_mfma_f32_16x16x32_f16(a0, wHi[0][ks], accH[0][0], 0,0,0);
      accH[1][0] = __builtin_amdgcn_mfma_f32_16x16x32_f16(a1, wHi[0][ks], accH[1][0], 0,0,0);
      accH[0][1] = __builtin_amdgcn_mfma_f32_16x16x32_f16(a0, wHi[1][ks], accH[0][1], 0,0,0);
      accH[1][1] = __builtin_amdgcn_mfma_f32_16x16x32_f16(a1, wHi[1][ks], accH[1][1], 0,0,0);
      accL[0][0] = __builtin_amdgcn_mfma_f32_16x16x32_f16(a0, wLo[0][ks], accL[0][0], 0,0,0);
      accL[1][0] = __builtin_amdgcn_mfma_f32_16x16x32_f16(a1, wLo[0][ks], accL[1][0], 0,0,0);
      accL[0][1] = __builtin_amdgcn_mfma_f32_16x16x32_f16(a0, wLo[1][ks], accL[0][1], 0,0,0);
      accL[1][1] = __builtin_amdgcn_mfma_f32_16x16x32_f16(a1, wLo[1][ks], accL[1][1], 0,0,0);
    }

    // C-layout (m89): col = lane&15, row = (lane>>4)*4 + i
    #pragma unroll
    for (int rt=0; rt<2; ++rt)
      #pragma unroll
      for (int ctt=0; ctt<2; ++ctt) {
        f32x4 v = accH[rt][ctt] + accL[rt][ctt]*(1.0f/2048.0f);
        const int col  = wcol*32 + ctt*16 + lcol;
        const int row0 = wrow*32 + rt*16 + lq*4;
        #pragma unroll
        for (int i=0; i<4; ++i) gates[row0+i][col] = v[i];
      }
    __syncthreads();   // (b)

    // ---- pointwise LSTM cell update ----
    const f32x4 gi = *reinterpret_cast<const f32x4*>(&gates[b_local][ 0 + u0]);
    const f32x4 gf = *reinterpret_cast<const f32x4*>(&gates[b_local][16 + u0]);
    const f32x4 gg = *reinterpret_cast<const f32x4*>(&gates[b_local][32 + u0]);
    const f32x4 go = *reinterpret_cast<const f32x4*>(&gates[b_local][48 + u0]);

    f16x4 hv4;
    float sp = 0.f;
    #pragma unroll
    for (int u=0; u<4; ++u) {
      float ai = gi[u] + biasv[ 0+u] + x*wihv[ 0+u];
      float af = gf[u] + biasv[ 4+u] + x*wihv[ 4+u];
      float ag = gg[u] + biasv[ 8+u] + x*wihv[ 8+u];
      float ao = go[u] + biasv[12+u] + x*wihv[12+u];
      float iv = sigm(ai);
      float fv = sigm(af);
      float gv = tanh_fast(ag);
      float ov = sigm(ao);
      float cn = fv*c[u] + iv*gv;
      c[u] = cn;
      float hv = ov*tanh_fast(cn);
      hv4[u] = (_Float16)hv;
      sp += hv*linw[u];
    }
    store_h8_llc(hw + (size_t)bg*512 + jh0, hv4);   // 8B write-through to LLC

    if (dec) {  // pred partial: 4-lane reduce, one atomic into d_out
      sp += __shfl_xor(sp, 1);
      sp += __shfl_xor(sp, 2);
      if ((tid & 3) == 0) {
        float v = sp + (hb == 0 ? linbv : 0.f);
        __hip_atomic_fetch_add(&out[(size_t)td*512 + bg], v,
                               __ATOMIC_RELAXED, __HIP_MEMORY_SCOPE_AGENT);
      }
    }

    // ---- row-group barrier: flag broadcast + ALL-wave poll, no handoff ----
    if (s != 1999) {
      asm volatile("s_waitcnt vmcnt(0)" ::: "memory");  // h stores/atomics acked
      __syncthreads();                                  // (c) block drained
      const int av = s + 1;
      if (tid == 0)
        __hip_atomic_store(myflag, av, __ATOMIC_RELAXED, __HIP_MEMORY_SCOPE_AGENT);
      while (!__all(__hip_atomic_load(pollp, __ATOMIC_RELAXED,
                                      __HIP_MEMORY_SCOPE_AGENT) >= av)) { }
      // each wave proceeds straight to next-step staging on its own detect
    }
  }
}

extern "C" void kernel_launch(void* const* d_in, const int* in_sizes, int n_in,
                              void* d_out, int out_size, void* d_ws, size_t ws_size,
                              hipStream_t stream) {
  const float* xin     = (const float*)d_in[0];
  const float* encWih  = (const float*)d_in[1];
  const float* encWhh  = (const float*)d_in[2];
  const float* enc_bih = (const float*)d_in[3];
  const float* enc_bhh = (const float*)d_in[4];
  const float* decWih  = (const float*)d_in[5];
  const float* decWhh  = (const float*)d_in[6];
  const float* dec_bih = (const float*)d_in[7];
  const float* dec_bhh = (const float*)d_in[8];
  const float* linW    = (const float*)d_in[9];
  const float* linb    = (const float*)d_in[10];
  float* out = (float*)d_out;
  char* ws = (char*)d_ws;
  int* flags = (int*)ws;                        // [0, 32KB): 256 x 128B flag lines
  _Float16* hbuf = (_Float16*)(ws + 32768);     // [32KB, +1MB): h double buffer

  // zero d_out (pred accumulator) + flags + h buffers, every launch
  init_zero<<<512, 256, 0, stream>>>(out, 1000*512, (float*)ws,
                                     (32768 + 2*512*512*2)/4);

  lstm_main<<<dim3(256), dim3(256), 0, stream>>>(
      xin, encWih, encWhh, enc_bih, enc_bhh,
      decWih, decWhh, dec_bih, dec_bhh,
      linW, linb, out, hbuf, flags);
}

// Round 12
// 12531.326 us; speedup vs baseline: 1.2449x; 1.1335x over previous
//
#include <hip/hip_runtime.h>

// LSTM seq2seq: 1000 enc + 1000 dec steps, B=512, H=512, IN=OUT=1.
// ROUND 12: 2-blocks/CU latency hiding. Grid 512 = 16 row-groups x 32
// col-blocks; block (rb,hb): rb=bid>>5 owns batch rows [rb*32,+32); hb=bid&31
// owns hidden cols [hb*16,+16) -> 64 gate cols (4 gates x 16, one gate/wave).
// LDS 41.5KB/block -> 2 blocks/CU (83KB<160KB), launch_bounds(256,2) caps
// VGPR at 256 -> 8 waves/CU resident. Co-resident blocks are in different
// row-groups with independent barrier phases: one block's MFMA/VALU fills
// the other's protocol/staging stalls (r6 budget: ~60% of 6.9us/step was
// CU-idle protocol+staging latency).
// Everything else = proven r6 protocol: single 16B-batch global_load_lds
// staging aux=17 (sc0|sc1 LLC-coherent), 8B->4B agent-atomic h stores,
// flag-broadcast barrier (wave0 poll + syncthreads handoff), fragment-order
// LDS, m89 C-layout, hi/lo fp16 weight split, HW transcendentals.
// [absmax 6.1e-5 rounds 5-11]

typedef _Float16 f16x8 __attribute__((ext_vector_type(8)));
typedef _Float16 f16x2 __attribute__((ext_vector_type(2)));
typedef float    f32x4 __attribute__((ext_vector_type(4)));
typedef unsigned long long u64;
typedef unsigned int u32;

// 16B global->LDS async copy, sc0|sc1: read at LLC coherence point,
// correct for cross-XCD producers regardless of block placement.
#define GLOAD_LDS16(gp, lp)                                                    \
  __builtin_amdgcn_global_load_lds(                                            \
      (const __attribute__((address_space(1))) void*)(gp),                     \
      (__attribute__((address_space(3))) void*)(lp), 16, 0, 17)

__device__ __forceinline__ void store_h4_llc(_Float16* p, f16x2 v) {
  __hip_atomic_store((u32*)p, __builtin_bit_cast(u32, v),
                     __ATOMIC_RELAXED, __HIP_MEMORY_SCOPE_AGENT);
}

// sigmoid(x) = rcp(1 + e^-x); tanh via e^(-2|x|): both overflow-safe.
__device__ __forceinline__ float sigm(float x) {
  return __builtin_amdgcn_rcpf(1.0f + __expf(-x));
}
__device__ __forceinline__ float tanh_fast(float x) {
  float r = __expf(-2.0f*fabsf(x));
  float t = (1.0f - r)*__builtin_amdgcn_rcpf(1.0f + r);
  return copysignf(t, x);
}

__global__ void init_zero(float* __restrict__ out, int nout,
                          float* __restrict__ wsf, int nws) {
  int i = blockIdx.x*blockDim.x + threadIdx.x;
  int st = gridDim.x*blockDim.x;
  // agent-scope write-through stores: nothing left dirty in any L2
  for (int j=i; j<nout; j+=st)
    __hip_atomic_store(&out[j], 0.f, __ATOMIC_RELAXED, __HIP_MEMORY_SCOPE_AGENT);
  for (int j=i; j<nws;  j+=st)
    __hip_atomic_store(&wsf[j], 0.f, __ATOMIC_RELAXED, __HIP_MEMORY_SCOPE_AGENT);
}

__global__ __launch_bounds__(256, 2) void lstm_main(
    const float* __restrict__ xin,                              // [1000][512]
    const float* __restrict__ encWih, const float* __restrict__ encWhh,
    const float* __restrict__ enc_bih, const float* __restrict__ enc_bhh,
    const float* __restrict__ decWih, const float* __restrict__ decWhh,
    const float* __restrict__ dec_bih, const float* __restrict__ dec_bhh,
    const float* __restrict__ linW, const float* __restrict__ linb,
    float* __restrict__ out,                                    // [1000][512]
    _Float16* __restrict__ hbuf,                                // [2][512][512]
    int* __restrict__ flags)                                    // 512 x 128B lines
{
  // h tile (32 rows x 512 k) in FRAGMENT order: chunk = (ks*2+half)*64 + lane,
  // half = 16-row A-fragment -> MFMA A reads are lane-linear ds_read_b128.
  __shared__ f16x8 h_lds[2048];     // 32 KB
  __shared__ float gates[32][68];   // 8704 B; +4 pad kills stride conflicts

  const int bid = blockIdx.x, tid = threadIdx.x;
  const int rb = bid >> 5, hb = bid & 31;              // rb 0..15, hb 0..31
  const int wid = tid >> 6, lane = tid & 63;           // wave = gate index
  const int lcol = lane & 15, lq = lane >> 4, kq = lq*8;

  // cell-update role: thread owns 2 cells (row b_local, hidden cols u0,u0+1)
  const int b_local = tid >> 3, u0 = (tid & 7)*2;
  const int bg = rb*32 + b_local;
  const int jh0 = hb*16 + u0;

  float linw[2];
  #pragma unroll
  for (int u=0; u<2; ++u) linw[u] = linW[jh0+u];
  const float linbv = linb[0];

  f16x8 wHi[16], wLo[16];           // this wave's gate, 16 k-steps: 128 VGPRs
  float biasv[8], wihv[8];          // [g*2+u]
  float c[2] = {0.f, 0.f};
  int* myflag = flags + bid*32;                        // own 128B line
  const int* pollp = flags + (rb*32 + (lane & 31))*32; // lane's producer line

  // staging source offsets: chunk c=i*256+tid -> fragment-order LDS
  int goff[8];
  #pragma unroll
  for (int i=0; i<8; ++i) {
    const int cch = i*256 + tid;
    const int frag = cch >> 6;                 // 0..31 = ks*2+half
    const int ks = frag >> 1, half = frag & 1;
    const int row_local = half*16 + (cch & 15);
    goff[i] = row_local*512 + ks*32 + ((cch >> 4) & 3)*8;
  }

  auto loadW = [&](const float* Whh, const float* bih, const float* bhh,
                   const float* Wih) {
    const int g = wid;                                 // wave = gate
    const float* wr = Whh + (size_t)(g*512 + hb*16 + lcol)*512;
    #pragma unroll
    for (int ks=0; ks<16; ++ks) {
      f16x8 hi, lo;
      #pragma unroll
      for (int i=0; i<8; ++i) {
        float w = wr[ks*32 + kq + i];
        _Float16 hh = (_Float16)w;
        float hf = (float)hh;
        float rem = (w - hf)*2048.0f;
        if (fabsf(hf) < 6.104e-5f) { hh = (_Float16)0.0f; rem = w*2048.0f; }
        hi[i] = hh; lo[i] = (_Float16)rem;
      }
      wHi[ks] = hi; wLo[ks] = lo;
    }
    #pragma unroll
    for (int gg=0; gg<4; ++gg)
      #pragma unroll
      for (int u=0; u<2; ++u) {
        int j = gg*512 + jh0 + u;
        biasv[gg*2+u] = bih[j] + bhh[j];
        wihv[gg*2+u]  = Wih[j];          // IN==1: Wih is [2048][1]
      }
  };

  loadW(encWhh, enc_bih, enc_bhh, encWih);

  for (int s=0; s<2000; ++s) {
    if (s == 1000) loadW(decWhh, dec_bih, dec_bhh, decWih);
    const bool dec = (s >= 1000);
    const int td = s - 1000;
    const _Float16* hr = hbuf + (size_t)((s+1)&1)*(512*512);  // reads h_{s-1}
    _Float16*       hw = hbuf + (size_t)( s   &1)*(512*512);  // writes h_s

    const _Float16* hrb = hr + (size_t)rb*32*512;   // this group's 32-row tile
    f16x8* ldst = &h_lds[(size_t)wid*64];           // wave-uniform base

    // hoist x: its LLC latency hides under staging drain
    float x;
    if (!dec) x = xin[(size_t)s*512 + bg];
    else if (td == 0) x = 0.0f;
    else x = __hip_atomic_load(&out[(size_t)(td-1)*512 + bg],
                               __ATOMIC_RELAXED, __HIP_MEMORY_SCOPE_AGENT);

    // ---- stage 32x512 fp16 h tile into LDS: ONE 8-load batch (max MLP) ----
    #pragma unroll
    for (int i=0; i<8; ++i)
      GLOAD_LDS16(hrb + goff[i], ldst + i*256);
    __syncthreads();   // (a) staged block-wide (compiler drains vmcnt)

    // ---- gates = h @ W^T: wave g computes [32 rows x 16 cols] of gate g ----
    f32x4 accH[2], accL[2];
    accH[0] = {0.f,0.f,0.f,0.f}; accH[1] = {0.f,0.f,0.f,0.f};
    accL[0] = {0.f,0.f,0.f,0.f}; accL[1] = {0.f,0.f,0.f,0.f};

    #pragma unroll
    for (int ks=0; ks<16; ++ks) {
      const f16x8 a0 = h_lds[(ks*2+0)*64 + lane];   // rows 0-15 fragment
      const f16x8 a1 = h_lds[(ks*2+1)*64 + lane];   // rows 16-31 fragment
      accH[0] = __builtin_amdgcn_mfma_f32_16x16x32_f16(a0, wHi[ks], accH[0], 0,0,0);
      accH[1] = __builtin_amdgcn_mfma_f32_16x16x32_f16(a1, wHi[ks], accH[1], 0,0,0);
      accL[0] = __builtin_amdgcn_mfma_f32_16x16x32_f16(a0, wLo[ks], accL[0], 0,0,0);
      accL[1] = __builtin_amdgcn_mfma_f32_16x16x32_f16(a1, wLo[ks], accL[1], 0,0,0);
    }

    // C-layout (m89): col = lane&15, row = (lane>>4)*4 + i
    #pragma unroll
    for (int rt=0; rt<2; ++rt) {
      f32x4 v = accH[rt] + accL[rt]*(1.0f/2048.0f);
      const int col  = wid*16 + lcol;        // gate wid, hidden col lcol
      const int row0 = rt*16 + lq*4;
      #pragma unroll
      for (int i=0; i<4; ++i) gates[row0+i][col] = v[i];
    }
    __syncthreads();   // (b)

    // ---- pointwise LSTM cell update (2 cells/thread) ----
    const float* grow = gates[b_local];
    f16x2 hv2;
    float sp = 0.f;
    #pragma unroll
    for (int u=0; u<2; ++u) {
      float ai = grow[ 0 + u0+u] + biasv[0+u] + x*wihv[0+u];
      float af = grow[16 + u0+u] + biasv[2+u] + x*wihv[2+u];
      float ag = grow[32 + u0+u] + biasv[4+u] + x*wihv[4+u];
      float ao = grow[48 + u0+u] + biasv[6+u] + x*wihv[6+u];
      float iv = sigm(ai);
      float fv = sigm(af);
      float gv = tanh_fast(ag);
      float ov = sigm(ao);
      float cn = fv*c[u] + iv*gv;
      c[u] = cn;
      float hv = ov*tanh_fast(cn);
      hv2[u] = (_Float16)hv;
      sp += hv*linw[u];
    }
    store_h4_llc(hw + (size_t)bg*512 + jh0, hv2);   // 4B write-through to LLC

    if (dec) {  // pred partial: 8-lane reduce (16 cols), one atomic into d_out
      sp += __shfl_xor(sp, 1);
      sp += __shfl_xor(sp, 2);
      sp += __shfl_xor(sp, 4);
      if ((tid & 7) == 0) {
        float v = sp + (hb == 0 ? linbv : 0.f);
        __hip_atomic_fetch_add(&out[(size_t)td*512 + bg], v,
                               __ATOMIC_RELAXED, __HIP_MEMORY_SCOPE_AGENT);
      }
    }

    // ---- row-group barrier (r6 form): wave0-only poll + handoff ----
    if (s != 1999) {
      asm volatile("s_waitcnt vmcnt(0)" ::: "memory");  // h stores/atomics acked
      __syncthreads();                                  // (c) block drained
      const int av = s + 1;
      if (tid == 0)
        __hip_atomic_store(myflag, av, __ATOMIC_RELAXED, __HIP_MEMORY_SCOPE_AGENT);
      if (wid == 0) {      // 64 lanes poll 32 producer flags (2 lanes/flag)
        while (!__all(__hip_atomic_load(pollp, __ATOMIC_RELAXED,
                                        __HIP_MEMORY_SCOPE_AGENT) >= av)) { }
      }
      __syncthreads();     // (d) handoff: all waves released by wave0
    }
  }
}

extern "C" void kernel_launch(void* const* d_in, const int* in_sizes, int n_in,
                              void* d_out, int out_size, void* d_ws, size_t ws_size,
                              hipStream_t stream) {
  const float* xin     = (const float*)d_in[0];
  const float* encWih  = (const float*)d_in[1];
  const float* encWhh  = (const float*)d_in[2];
  const float* enc_bih = (const float*)d_in[3];
  const float* enc_bhh = (const float*)d_in[4];
  const float* decWih  = (const float*)d_in[5];
  const float* decWhh  = (const float*)d_in[6];
  const float* dec_bih = (const float*)d_in[7];
  const float* dec_bhh = (const float*)d_in[8];
  const float* linW    = (const float*)d_in[9];
  const float* linb    = (const float*)d_in[10];
  float* out = (float*)d_out;
  char* ws = (char*)d_ws;
  int* flags = (int*)ws;                        // [0, 64KB): 512 x 128B flag lines
  _Float16* hbuf = (_Float16*)(ws + 65536);     // [64KB, +1MB): h double buffer

  // zero d_out (pred accumulator) + flags + h buffers, every launch
  init_zero<<<512, 256, 0, stream>>>(out, 1000*512, (float*)ws,
                                     (65536 + 2*512*512*2)/4);

  lstm_main<<<dim3(512), dim3(256), 0, stream>>>(
      xin, encWih, encWhh, enc_bih, enc_bhh,
      decWih, decWhh, dec_bih, dec_bhh,
      linW, linb, out, hbuf, flags);
}